// Round 4
// baseline (961.681 us; speedup 1.0000x reference)
//
#include <hip/hip_runtime.h>
#include <math.h>

// Problem constants (fixed by setup_inputs: b=2, H=W=T=24, c=512, heads=8)
constexpr int Cc     = 512;
constexpr int NHEAD  = 8;
constexpr int HD     = 64;
constexpr int NTOK   = 13824;          // tokens per batch element (24^3)
constexpr int BATCH  = 2;
constexpr int M_TOT  = BATCH * NTOK;   // 27648 total rows
constexpr int QKV_LD = 3 * Cc;         // 1536
constexpr int SEQLEN = 576;            // 24*24 per decomposed attention
constexpr int NTILE  = SEQLEN / 64;    // 9 k-tiles of 64
constexpr int KT     = 16;             // K=512 / 32 per MFMA step (all GEMMs)

// q-plane scale: sqrt(hd)=8 folded with log2(e) so softmax uses exp2
#define QSCALE 11.541560327111707f

typedef short s16x8 __attribute__((ext_vector_type(8)));
typedef float f32x4 __attribute__((ext_vector_type(4)));

__device__ __forceinline__ unsigned short f2bf(float f) {
  unsigned u = __float_as_uint(f);
  unsigned r = u + 0x7fffu + ((u >> 16) & 1u);
  return (unsigned short)(r >> 16);
}
__device__ __forceinline__ float bf2f(unsigned short b) {
  return __uint_as_float(((unsigned)b) << 16);
}

// ---------------------------------------------------------------------------
// Convert fp32 row-major A[M][512] into fragment-major bf16 (hi, optional lo).
// Fragment (mt,kt): lane l owns A[mt*16+(l&15)][kt*32+8*(l>>4)+j].
// ---------------------------------------------------------------------------
template<bool WRITE_LO>
__global__ __launch_bounds__(256)
void conv_a_frag(const float* __restrict__ src, s16x8* __restrict__ dh,
                 s16x8* __restrict__ dl) {
  int g  = blockIdx.x * 256 + threadIdx.x;
  int l  = g & 63;
  int t  = g >> 6;
  int kt = t & (KT - 1);
  int mt = t >> 4;
  const float* p = src + (size_t)(mt * 16 + (l & 15)) * 512 + kt * 32 + (l >> 4) * 8;
  float4 a = *(const float4*)p;
  float4 b = *(const float4*)(p + 4);
  float xs[8] = {a.x, a.y, a.z, a.w, b.x, b.y, b.z, b.w};
  s16x8 h, lo;
#pragma unroll
  for (int j = 0; j < 8; ++j) {
    unsigned short hh = f2bf(xs[j]);
    h[j] = (short)hh;
    if (WRITE_LO) lo[j] = (short)f2bf(xs[j] - bf2f(hh));
  }
  dh[g] = h;
  if (WRITE_LO) dl[g] = lo;
}

// ---------------------------------------------------------------------------
// Convert fp32 row-major B[512][N] into fragment-major bf16 (hi, optional lo).
// ---------------------------------------------------------------------------
template<bool WRITE_LO>
__global__ __launch_bounds__(256)
void conv_b_frag(const float* __restrict__ src, s16x8* __restrict__ dh,
                 s16x8* __restrict__ dl, int N) {
  int g  = blockIdx.x * 256 + threadIdx.x;
  int l  = g & 63;
  int t  = g >> 6;
  int kt = t & (KT - 1);
  int nt = t >> 4;
  int col  = nt * 16 + (l & 15);
  int row0 = kt * 32 + (l >> 4) * 8;
  s16x8 h, lo;
#pragma unroll
  for (int j = 0; j < 8; ++j) {
    float v = src[(size_t)(row0 + j) * N + col];
    unsigned short hh = f2bf(v);
    h[j] = (short)hh;
    if (WRITE_LO) lo[j] = (short)f2bf(v - bf2f(hh));
  }
  dh[g] = h;
  if (WRITE_LO) dl[g] = lo;
}

// ---------------------------------------------------------------------------
// No-LDS MFMA GEMM on fragment-major bf16 operands.
// SPLIT==3: C = Ah*Bh + Al*Bh + Ah*Bl ; SPLIT==1: C = Ah*Bh.
// MODE 0: write fp32 C row-major.
// MODE 1: qk epilogue -> head-major bf16 hi/lo planes (q scaled by QSCALE).
// MODE 2: v epilogue  -> head-major bf16 hi plane only.
// ---------------------------------------------------------------------------
template<int SPLIT, int MODE>
__global__ __launch_bounds__(256)
void gemm_frag(const s16x8* __restrict__ Ah, const s16x8* __restrict__ Al,
               const s16x8* __restrict__ Bh, const s16x8* __restrict__ Bl,
               float* __restrict__ C,
               unsigned short* __restrict__ p0, unsigned short* __restrict__ p1,
               unsigned short* __restrict__ p2, unsigned short* __restrict__ p3,
               int nbx, int n0, int N_ld, int ntoff) {
  // bijective XCD swizzle (all grids are multiples of 8)
  int nwg = gridDim.x;
  int cpx = nwg >> 3;
  int bid = blockIdx.x;
  int swz = (bid & 7) * cpx + (bid >> 3);
  int bx = swz % nbx;
  int by = swz / nbx;

  int tid  = threadIdx.x;
  int lane = tid & 63;
  int w    = tid >> 6;
  int wm   = w & 1;
  int wn   = w >> 1;
  int mt0  = by * 8 + wm * 4;
  int ntG  = ntoff + bx * 8 + wn * 4;

  const f32x4 fz = {0.0f, 0.0f, 0.0f, 0.0f};
  f32x4 acc[4][4];
#pragma unroll
  for (int mi = 0; mi < 4; ++mi)
#pragma unroll
    for (int ni = 0; ni < 4; ++ni) acc[mi][ni] = fz;

#pragma unroll 2
  for (int kt = 0; kt < KT; ++kt) {
    s16x8 ah[4], bh[4];
#pragma unroll
    for (int mi = 0; mi < 4; ++mi)
      ah[mi] = Ah[(size_t)(((mt0 + mi) * KT + kt) * 64 + lane)];
#pragma unroll
    for (int ni = 0; ni < 4; ++ni)
      bh[ni] = Bh[(size_t)(((ntG + ni) * KT + kt) * 64 + lane)];

    if constexpr (SPLIT == 3) {
      s16x8 al[4], bl[4];
#pragma unroll
      for (int mi = 0; mi < 4; ++mi)
        al[mi] = Al[(size_t)(((mt0 + mi) * KT + kt) * 64 + lane)];
#pragma unroll
      for (int ni = 0; ni < 4; ++ni)
        bl[ni] = Bl[(size_t)(((ntG + ni) * KT + kt) * 64 + lane)];
#pragma unroll
      for (int mi = 0; mi < 4; ++mi)
#pragma unroll
        for (int ni = 0; ni < 4; ++ni) {
          acc[mi][ni] = __builtin_amdgcn_mfma_f32_16x16x32_bf16(ah[mi], bh[ni], acc[mi][ni], 0, 0, 0);
          acc[mi][ni] = __builtin_amdgcn_mfma_f32_16x16x32_bf16(al[mi], bh[ni], acc[mi][ni], 0, 0, 0);
          acc[mi][ni] = __builtin_amdgcn_mfma_f32_16x16x32_bf16(ah[mi], bl[ni], acc[mi][ni], 0, 0, 0);
        }
    } else {
#pragma unroll
      for (int mi = 0; mi < 4; ++mi)
#pragma unroll
        for (int ni = 0; ni < 4; ++ni)
          acc[mi][ni] = __builtin_amdgcn_mfma_f32_16x16x32_bf16(ah[mi], bh[ni], acc[mi][ni], 0, 0, 0);
    }
  }

  int lg = lane >> 4, l15 = lane & 15;
  if constexpr (MODE == 0) {
    // D layout: col = lane&15, row = 4*(lane>>4)+r
#pragma unroll
    for (int mi = 0; mi < 4; ++mi) {
#pragma unroll
      for (int r = 0; r < 4; ++r) {
        int row = by * 128 + wm * 64 + mi * 16 + lg * 4 + r;
        float* cp = C + (size_t)row * N_ld + n0 + bx * 128 + wn * 64 + l15;
#pragma unroll
        for (int ni = 0; ni < 4; ++ni) cp[ni * 16] = acc[mi][ni][r];
      }
    }
  } else {
    int colb = bx * 128 + wn * 64;      // 64-aligned: whole wave = one head
    int head = (colb >> 6) & 7;
    const bool isq = (MODE == 1) && (colb < 512);
    unsigned short* Hp;
    unsigned short* Lp = nullptr;
    float sc = 1.0f;
    if (MODE == 2)      { Hp = p0; }
    else if (isq)       { Hp = p0; Lp = p1; sc = QSCALE; }
    else                { Hp = p2; Lp = p3; }
    size_t hb = (size_t)head * ((size_t)M_TOT * 64);
#pragma unroll
    for (int mi = 0; mi < 4; ++mi) {
#pragma unroll
      for (int r = 0; r < 4; ++r) {
        int row = by * 128 + wm * 64 + mi * 16 + lg * 4 + r;
        size_t base = hb + (size_t)row * 64;
#pragma unroll
        for (int ni = 0; ni < 4; ++ni) {
          int d = ni * 16 + l15;
          float v = acc[mi][ni][r] * sc;
          unsigned short hh = f2bf(v);
          Hp[base + d] = hh;
          if (MODE == 1) Lp[base + d] = f2bf(v - bf2f(hh));
        }
      }
    }
  }
}

// ---------------------------------------------------------------------------
// MFMA flash attention reading pre-split head-major bf16 planes.
// Block = 4 waves, handles (be, head, qt=64 q-rows). Staging = pure copies.
// Softmax in base-2 (scale folded into Q plane). XCD-swizzled grid: the 9
// q-tile siblings of each (be,head) share one XCD's L2 for K/V.
// ---------------------------------------------------------------------------
__global__ __launch_bounds__(256, 5)
void attn_mfma(const unsigned short* __restrict__ QH, const unsigned short* __restrict__ QL,
               const unsigned short* __restrict__ KH, const unsigned short* __restrict__ KL,
               const unsigned short* __restrict__ VH,
               float* __restrict__ osum,
               int str1, int str2, int strE, int accumulate) {
  __shared__ __align__(16) unsigned short KhS[4096];
  __shared__ __align__(16) unsigned short KlS[4096];
  __shared__ __align__(16) unsigned short VtS[4096];  // V transposed [d][kcol]
  __shared__ __align__(16) unsigned short PsS[4096];  // P bf16 [q][kcol]

  // bijective XCD swizzle: grid 3456 = 8 * 432; 432 = 48 (be,head) groups
  int bi = (blockIdx.x & 7) * 432 + (blockIdx.x >> 3);
  const int qt   = bi % NTILE;
  const int head = (bi / NTILE) & 7;
  const int be   = bi / (NTILE * NHEAD);
  const int bb   = be / 24;
  const int e    = be % 24;

  const int tid  = threadIdx.x;
  const int w    = tid >> 6;
  const int lane = tid & 63;
  const int l15  = lane & 15;
  const int lg   = lane >> 4;   // 0..3

  const size_t base_tok = (size_t)bb * NTOK + (size_t)e * strE;
  const size_t pb = ((size_t)head * M_TOT + base_tok) * 64;
  const unsigned short* qhp = QH + pb;
  const unsigned short* qlp = QL + pb;
  const unsigned short* khp = KH + pb;
  const unsigned short* klp = KL + pb;
  const unsigned short* vhp = VH + pb;

  // ---- load Q fragments (pre-scaled, pre-split) ----
  s16x8 qh[2], ql[2];
  {
    int s  = qt * 64 + w * 16 + l15;
    size_t no = (size_t)((s / 24) * str1 + (s % 24) * str2) * 64 + lg * 8;
    qh[0] = *(const s16x8*)(qhp + no);
    qh[1] = *(const s16x8*)(qhp + no + 32);
    ql[0] = *(const s16x8*)(qlp + no);
    ql[1] = *(const s16x8*)(qlp + no + 32);
  }

  float m_run[4], l_run[4];
  f32x4 Ov[4];
  const f32x4 fzero = {0.0f, 0.0f, 0.0f, 0.0f};
#pragma unroll
  for (int rr = 0; rr < 4; ++rr) { m_run[rr] = -1e30f; l_run[rr] = 0.0f; }
#pragma unroll
  for (int n = 0; n < 4; ++n) Ov[n] = fzero;

  for (int kt = 0; kt < NTILE; ++kt) {
    __syncthreads();
    // ---- stage K hi/lo (pure copy, swizzled) ----
    {
      int cc = tid & 7;      // 16B chunk (d0 = cc*8)
      int r0 = tid >> 3;     // 0..31
#pragma unroll
      for (int hf = 0; hf < 2; ++hf) {
        int r = r0 + hf * 32;
        int s = kt * 64 + r;
        size_t no = (size_t)((s / 24) * str1 + (s % 24) * str2) * 64 + cc * 8;
        int woff = (r << 6) + ((cc ^ (r & 7)) << 3);
        *(s16x8*)&KhS[woff] = *(const s16x8*)(khp + no);
        *(s16x8*)&KlS[woff] = *(const s16x8*)(klp + no);
      }
    }
    // ---- stage V transposed (copy + u32 pack of token pairs) ----
    {
      int rp = (tid & 31) * 2;   // token pair
      int cb = tid >> 5;         // d chunk 0..7
      int sa = kt * 64 + rp, sb = sa + 1;
      size_t na = (size_t)((sa / 24) * str1 + (sa % 24) * str2) * 64 + cb * 8;
      size_t nb = (size_t)((sb / 24) * str1 + (sb % 24) * str2) * 64 + cb * 8;
      s16x8 va = *(const s16x8*)(vhp + na);
      s16x8 vb = *(const s16x8*)(vhp + nb);
#pragma unroll
      for (int j = 0; j < 8; ++j) {
        int d = cb * 8 + j;
        unsigned pk = (unsigned)(unsigned short)va[j] |
                      ((unsigned)(unsigned short)vb[j] << 16);
        int off = (d << 6) + (((rp >> 3) ^ (d & 7)) << 3) + (rp & 7);
        *(unsigned*)&VtS[off] = pk;
      }
    }
    __syncthreads();

    // ---- S = (Qh+Ql)(Kh+Kl)^T via 3 MFMA terms (log2-scaled logits) ----
    f32x4 Sv[4];
#pragma unroll
    for (int n = 0; n < 4; ++n) Sv[n] = fzero;
#pragma unroll
    for (int ks = 0; ks < 2; ++ks) {
#pragma unroll
      for (int n = 0; n < 4; ++n) {
        int krow = (n << 4) + l15;
        int off  = (krow << 6) + (((ks * 4 + lg) ^ (krow & 7)) << 3);
        s16x8 kfh = *(const s16x8*)&KhS[off];
        s16x8 kfl = *(const s16x8*)&KlS[off];
        Sv[n] = __builtin_amdgcn_mfma_f32_16x16x32_bf16(qh[ks], kfh, Sv[n], 0, 0, 0);
        Sv[n] = __builtin_amdgcn_mfma_f32_16x16x32_bf16(ql[ks], kfh, Sv[n], 0, 0, 0);
        Sv[n] = __builtin_amdgcn_mfma_f32_16x16x32_bf16(qh[ks], kfl, Sv[n], 0, 0, 0);
      }
    }

    // ---- online softmax (base 2) ----
    float alpha[4];
#pragma unroll
    for (int rr = 0; rr < 4; ++rr) {
      float m0 = fmaxf(fmaxf(Sv[0][rr], Sv[1][rr]), fmaxf(Sv[2][rr], Sv[3][rr]));
      m0 = fmaxf(m0, __shfl_xor(m0, 1));
      m0 = fmaxf(m0, __shfl_xor(m0, 2));
      m0 = fmaxf(m0, __shfl_xor(m0, 4));
      m0 = fmaxf(m0, __shfl_xor(m0, 8));
      float mn = fmaxf(m_run[rr], m0);
      alpha[rr] = exp2f(m_run[rr] - mn);
      m_run[rr] = mn;
    }
#pragma unroll
    for (int rr = 0; rr < 4; ++rr) {
      float ts = 0.0f;
#pragma unroll
      for (int n = 0; n < 4; ++n) {
        float p = exp2f(Sv[n][rr] - m_run[rr]);
        Sv[n][rr] = p;
        ts += p;
      }
      ts += __shfl_xor(ts, 1);
      ts += __shfl_xor(ts, 2);
      ts += __shfl_xor(ts, 4);
      ts += __shfl_xor(ts, 8);
      l_run[rr] = l_run[rr] * alpha[rr] + ts;
#pragma unroll
      for (int n = 0; n < 4; ++n) Ov[n][rr] *= alpha[rr];
    }

    // ---- write P (bf16) to LDS (own-wave rows; same-wave read below) ----
    {
      int prow_base = (w << 4) + (lg << 2);
#pragma unroll
      for (int n = 0; n < 4; ++n) {
        int col = (n << 4) + l15;
#pragma unroll
        for (int rr = 0; rr < 4; ++rr) {
          int row = prow_base + rr;
          int off = (row << 6) + (((col >> 3) ^ (row & 7)) << 3) + (col & 7);
          PsS[off] = f2bf(Sv[n][rr]);
        }
      }
    }

    // ---- O += P @ V ----
#pragma unroll
    for (int ks = 0; ks < 2; ++ks) {
      int arow = (w << 4) + l15;
      int aoff = (arow << 6) + (((ks * 4 + lg) ^ (arow & 7)) << 3);
      s16x8 pa = *(const s16x8*)&PsS[aoff];
#pragma unroll
      for (int n = 0; n < 4; ++n) {
        int vrow = (n << 4) + l15;
        int voff = (vrow << 6) + (((ks * 4 + lg) ^ (vrow & 7)) << 3);
        s16x8 vb = *(const s16x8*)&VtS[voff];
        Ov[n] = __builtin_amdgcn_mfma_f32_16x16x32_bf16(pa, vb, Ov[n], 0, 0, 0);
      }
    }
  }

  // ---- epilogue ----
  float inv[4];
#pragma unroll
  for (int rr = 0; rr < 4; ++rr) inv[rr] = 1.0f / l_run[rr];
#pragma unroll
  for (int rr = 0; rr < 4; ++rr) {
    int srow = qt * 64 + (w << 4) + (lg << 2) + rr;
    int no = (srow / 24) * str1 + (srow % 24) * str2;
    float* orow = osum + (base_tok + no) * (size_t)Cc + head * HD + l15;
#pragma unroll
    for (int n = 0; n < 4; ++n) {
      float* op = orow + (n << 4);
      float v = Ov[n][rr] * inv[rr];
      if (accumulate) v += *op;
      *op = v;
    }
  }
}

// ---------------------------------------------------------------------------
extern "C" void kernel_launch(void* const* d_in, const int* in_sizes, int n_in,
                              void* d_out, int out_size, void* d_ws, size_t ws_size,
                              hipStream_t stream) {
  (void)in_sizes; (void)n_in; (void)out_size; (void)ws_size;
  const float* x      = (const float*)d_in[0];
  const float* w_qkv  = (const float*)d_in[1];
  const float* w_proj = (const float*)d_in[2];
  float* out = (float*)d_out;

  // ---- workspace layout (peak ~201 MB) ----
  char* ws = (char*)d_ws;
  constexpr size_t PL_E = (size_t)NHEAD * M_TOT * 64;     // 14,155,776 elems
  constexpr size_t PL_B = PL_E * 2;                       // 28,311,552 B
  unsigned short* QHp = (unsigned short*)ws;
  unsigned short* QLp = QHp + PL_E;
  unsigned short* KHp = QHp + 2 * PL_E;
  unsigned short* KLp = QHp + 3 * PL_E;
  unsigned short* VHp = QHp + 4 * PL_E;
  float* osum = (float*)(ws + 5 * PL_B);                  // 56.6 MB
  s16x8* Ah   = (s16x8*)osum;                             // overlay (dead before osum)
  s16x8* Al   = (s16x8*)(ws + 5 * PL_B + PL_B);
  s16x8* Bh   = (s16x8*)(ws + 5 * PL_B + 2 * PL_B);       // w_qkv hi (1.57 MB)
  s16x8* Bl   = (s16x8*)(ws + 5 * PL_B + 2 * PL_B + 1572864);
  s16x8* Oh   = (s16x8*)ws;                               // overlay QH (dead after attn)
  s16x8* Ph   = (s16x8*)(ws + PL_B);                      // w_proj (0.52 MB)

  unsigned short* nu = nullptr;

  // 1) operand conversion (fragment-major)
  conv_a_frag<true><<<M_TOT * 64 / 256, 256, 0, stream>>>(x, Ah, Al);
  conv_b_frag<true><<<KT * (QKV_LD / 16) * 64 / 256, 256, 0, stream>>>(w_qkv, Bh, Bl, QKV_LD);

  // 2) qkv GEMM -> bf16 planes (q,k split hi/lo + q scaled; v plain)
  gemm_frag<3, 1><<<(M_TOT / 128) * 8, 256, 0, stream>>>(
      Ah, Al, Bh, Bl, nullptr, QHp, QLp, KHp, KLp, 8, 0, 0, 0);
  gemm_frag<1, 2><<<(M_TOT / 128) * 4, 256, 0, stream>>>(
      Ah, nullptr, Bh, nullptr, nullptr, VHp, nu, nu, nu, 4, 0, 0, 64);

  // 3) three decomposed attentions, accumulated into osum
  attn_mfma<<<48 * NHEAD * NTILE, 256, 0, stream>>>(QHp, QLp, KHp, KLp, VHp, osum, 576, 24, 1, 0);
  attn_mfma<<<48 * NHEAD * NTILE, 256, 0, stream>>>(QHp, QLp, KHp, KLp, VHp, osum, 576, 1, 24, 1);
  attn_mfma<<<48 * NHEAD * NTILE, 256, 0, stream>>>(QHp, QLp, KHp, KLp, VHp, osum, 24, 1, 576, 1);

  // 4) proj GEMM: out = osum @ w_proj (plain bf16)
  conv_a_frag<false><<<M_TOT * 64 / 256, 256, 0, stream>>>(osum, Oh, nullptr);
  conv_b_frag<false><<<KT * (Cc / 16) * 64 / 256, 256, 0, stream>>>(w_proj, Ph, nullptr, Cc);
  gemm_frag<1, 0><<<(M_TOT / 128) * 4, 256, 0, stream>>>(
      Oh, nullptr, Ph, nullptr, out, nu, nu, nu, nu, 4, 0, Cc, 0);
}

// Round 5
// 661.900 us; speedup vs baseline: 1.4529x; 1.4529x over previous
//
#include <hip/hip_runtime.h>
#include <math.h>

// Problem constants (fixed by setup_inputs: b=2, H=W=T=24, c=512, heads=8)
constexpr int Cc     = 512;
constexpr int NHEAD  = 8;
constexpr int HD     = 64;
constexpr int NTOK   = 13824;          // tokens per batch element (24^3)
constexpr int BATCH  = 2;
constexpr int M_TOT  = BATCH * NTOK;   // 27648 total rows
constexpr int QKV_LD = 3 * Cc;         // 1536
constexpr int SEQLEN = 576;            // 24*24 per decomposed attention
constexpr int NTILE  = SEQLEN / 64;    // 9 k-tiles of 64
constexpr int KT     = 16;             // K=512 / 32 per MFMA step (all GEMMs)

// q-plane scale: sqrt(hd)=8 folded with log2(e) so softmax uses exp2
#define QSCALE 11.541560327111707f

typedef short s16x8 __attribute__((ext_vector_type(8)));
typedef float f32x4 __attribute__((ext_vector_type(4)));

__device__ __forceinline__ unsigned short f2bf(float f) {
  unsigned u = __float_as_uint(f);
  unsigned r = u + 0x7fffu + ((u >> 16) & 1u);
  return (unsigned short)(r >> 16);
}
__device__ __forceinline__ float bf2f(unsigned short b) {
  return __uint_as_float(((unsigned)b) << 16);
}

// ---------------------------------------------------------------------------
// Convert fp32 row-major A[M][512] into fragment-major bf16 (hi, optional lo).
// Fragment (mt,kt): lane l owns A[mt*16+(l&15)][kt*32+8*(l>>4)+j].
// ---------------------------------------------------------------------------
template<bool WRITE_LO>
__global__ __launch_bounds__(256)
void conv_a_frag(const float* __restrict__ src, s16x8* __restrict__ dh,
                 s16x8* __restrict__ dl) {
  int g  = blockIdx.x * 256 + threadIdx.x;
  int l  = g & 63;
  int t  = g >> 6;
  int kt = t & (KT - 1);
  int mt = t >> 4;
  const float* p = src + (size_t)(mt * 16 + (l & 15)) * 512 + kt * 32 + (l >> 4) * 8;
  float4 a = *(const float4*)p;
  float4 b = *(const float4*)(p + 4);
  float xs[8] = {a.x, a.y, a.z, a.w, b.x, b.y, b.z, b.w};
  s16x8 h, lo;
#pragma unroll
  for (int j = 0; j < 8; ++j) {
    unsigned short hh = f2bf(xs[j]);
    h[j] = (short)hh;
    if (WRITE_LO) lo[j] = (short)f2bf(xs[j] - bf2f(hh));
  }
  dh[g] = h;
  if (WRITE_LO) dl[g] = lo;
}

// ---------------------------------------------------------------------------
// Convert fp32 row-major B[512][N] into fragment-major bf16 (hi, optional lo).
// ---------------------------------------------------------------------------
template<bool WRITE_LO>
__global__ __launch_bounds__(256)
void conv_b_frag(const float* __restrict__ src, s16x8* __restrict__ dh,
                 s16x8* __restrict__ dl, int N) {
  int g  = blockIdx.x * 256 + threadIdx.x;
  int l  = g & 63;
  int t  = g >> 6;
  int kt = t & (KT - 1);
  int nt = t >> 4;
  int col  = nt * 16 + (l & 15);
  int row0 = kt * 32 + (l >> 4) * 8;
  s16x8 h, lo;
#pragma unroll
  for (int j = 0; j < 8; ++j) {
    float v = src[(size_t)(row0 + j) * N + col];
    unsigned short hh = f2bf(v);
    h[j] = (short)hh;
    if (WRITE_LO) lo[j] = (short)f2bf(v - bf2f(hh));
  }
  dh[g] = h;
  if (WRITE_LO) dl[g] = lo;
}

// ---------------------------------------------------------------------------
// Sum three attention O planes (head-major bf16) -> proj A fragments.
// ---------------------------------------------------------------------------
__global__ __launch_bounds__(256)
void conv_o_frag(const unsigned short* __restrict__ O0,
                 const unsigned short* __restrict__ O1,
                 const unsigned short* __restrict__ O2,
                 s16x8* __restrict__ dh) {
  int g  = blockIdx.x * 256 + threadIdx.x;
  int l  = g & 63;
  int t  = g >> 6;
  int kt = t & (KT - 1);
  int mt = t >> 4;
  int row = mt * 16 + (l & 15);
  int c0  = kt * 32 + (l >> 4) * 8;     // 8-contiguous, within one head's d-range
  int head = c0 >> 6;
  size_t off = ((size_t)head * M_TOT + row) * 64 + (c0 & 63);
  s16x8 a = *(const s16x8*)(O0 + off);
  s16x8 b = *(const s16x8*)(O1 + off);
  s16x8 c = *(const s16x8*)(O2 + off);
  s16x8 h;
#pragma unroll
  for (int j = 0; j < 8; ++j) {
    float v = bf2f((unsigned short)a[j]) + bf2f((unsigned short)b[j]) +
              bf2f((unsigned short)c[j]);
    h[j] = (short)f2bf(v);
  }
  dh[g] = h;
}

// ---------------------------------------------------------------------------
// No-LDS MFMA GEMM on fragment-major bf16 operands.
// SPLIT==3: C = Ah*Bh + Al*Bh + Ah*Bl ; SPLIT==1: C = Ah*Bh.
// MODE 0: fp32 C row-major. MODE 1: qk -> bf16 hi/lo planes (q scaled).
// MODE 2: v -> bf16 hi plane.
// ---------------------------------------------------------------------------
template<int SPLIT, int MODE>
__global__ __launch_bounds__(256)
void gemm_frag(const s16x8* __restrict__ Ah, const s16x8* __restrict__ Al,
               const s16x8* __restrict__ Bh, const s16x8* __restrict__ Bl,
               float* __restrict__ C,
               unsigned short* __restrict__ p0, unsigned short* __restrict__ p1,
               unsigned short* __restrict__ p2, unsigned short* __restrict__ p3,
               int nbx, int n0, int N_ld, int ntoff) {
  int nwg = gridDim.x;
  int cpx = nwg >> 3;
  int bid = blockIdx.x;
  int swz = (bid & 7) * cpx + (bid >> 3);
  int bx = swz % nbx;
  int by = swz / nbx;

  int tid  = threadIdx.x;
  int lane = tid & 63;
  int w    = tid >> 6;
  int wm   = w & 1;
  int wn   = w >> 1;
  int mt0  = by * 8 + wm * 4;
  int ntG  = ntoff + bx * 8 + wn * 4;

  const f32x4 fz = {0.0f, 0.0f, 0.0f, 0.0f};
  f32x4 acc[4][4];
#pragma unroll
  for (int mi = 0; mi < 4; ++mi)
#pragma unroll
    for (int ni = 0; ni < 4; ++ni) acc[mi][ni] = fz;

#pragma unroll 2
  for (int kt = 0; kt < KT; ++kt) {
    s16x8 ah[4], bh[4];
#pragma unroll
    for (int mi = 0; mi < 4; ++mi)
      ah[mi] = Ah[(size_t)(((mt0 + mi) * KT + kt) * 64 + lane)];
#pragma unroll
    for (int ni = 0; ni < 4; ++ni)
      bh[ni] = Bh[(size_t)(((ntG + ni) * KT + kt) * 64 + lane)];

    if constexpr (SPLIT == 3) {
      s16x8 al[4], bl[4];
#pragma unroll
      for (int mi = 0; mi < 4; ++mi)
        al[mi] = Al[(size_t)(((mt0 + mi) * KT + kt) * 64 + lane)];
#pragma unroll
      for (int ni = 0; ni < 4; ++ni)
        bl[ni] = Bl[(size_t)(((ntG + ni) * KT + kt) * 64 + lane)];
#pragma unroll
      for (int mi = 0; mi < 4; ++mi)
#pragma unroll
        for (int ni = 0; ni < 4; ++ni) {
          acc[mi][ni] = __builtin_amdgcn_mfma_f32_16x16x32_bf16(ah[mi], bh[ni], acc[mi][ni], 0, 0, 0);
          acc[mi][ni] = __builtin_amdgcn_mfma_f32_16x16x32_bf16(al[mi], bh[ni], acc[mi][ni], 0, 0, 0);
          acc[mi][ni] = __builtin_amdgcn_mfma_f32_16x16x32_bf16(ah[mi], bl[ni], acc[mi][ni], 0, 0, 0);
        }
    } else {
#pragma unroll
      for (int mi = 0; mi < 4; ++mi)
#pragma unroll
        for (int ni = 0; ni < 4; ++ni)
          acc[mi][ni] = __builtin_amdgcn_mfma_f32_16x16x32_bf16(ah[mi], bh[ni], acc[mi][ni], 0, 0, 0);
    }
  }

  int lg = lane >> 4, l15 = lane & 15;
  if constexpr (MODE == 0) {
#pragma unroll
    for (int mi = 0; mi < 4; ++mi) {
#pragma unroll
      for (int r = 0; r < 4; ++r) {
        int row = by * 128 + wm * 64 + mi * 16 + lg * 4 + r;
        float* cp = C + (size_t)row * N_ld + n0 + bx * 128 + wn * 64 + l15;
#pragma unroll
        for (int ni = 0; ni < 4; ++ni) cp[ni * 16] = acc[mi][ni][r];
      }
    }
  } else {
    int colb = bx * 128 + wn * 64;
    int head = (colb >> 6) & 7;
    const bool isq = (MODE == 1) && (colb < 512);
    unsigned short* Hp;
    unsigned short* Lp = nullptr;
    float sc = 1.0f;
    if (MODE == 2)      { Hp = p0; }
    else if (isq)       { Hp = p0; Lp = p1; sc = QSCALE; }
    else                { Hp = p2; Lp = p3; }
    size_t hb = (size_t)head * ((size_t)M_TOT * 64);
#pragma unroll
    for (int mi = 0; mi < 4; ++mi) {
#pragma unroll
      for (int r = 0; r < 4; ++r) {
        int row = by * 128 + wm * 64 + mi * 16 + lg * 4 + r;
        size_t base = hb + (size_t)row * 64;
#pragma unroll
        for (int ni = 0; ni < 4; ++ni) {
          int d = ni * 16 + l15;
          float v = acc[mi][ni][r] * sc;
          unsigned short hh = f2bf(v);
          Hp[base + d] = hh;
          if (MODE == 1) Lp[base + d] = f2bf(v - bf2f(hh));
        }
      }
    }
  }
}

// ---------------------------------------------------------------------------
// Deferred-softmax MFMA attention. Block = 4 waves, (be, head, qt=64 rows).
// Loop A: 9 K-tiles, double-buffered reg->LDS staging, raw barrier with
//   counted lgkm (no vmcnt drain), 24 MFMA/tile into S[9][4] regs (144 VGPR).
// One softmax (in-reg max/sum + single 4-shuffle reduce per row, exp2).
// Loop B: 9 V-tiles (double-buffered; t0 loads issued pre-softmax), P via
//   own-wave LDS round-trip, 8 MFMA/tile. Epilogue: LDS transpose -> bf16
//   plane written as contiguous 128B rows (no RMW; per-pass buffer).
// ---------------------------------------------------------------------------
__global__ __launch_bounds__(256, 2)
void attn_def(const unsigned short* __restrict__ QH, const unsigned short* __restrict__ QL,
              const unsigned short* __restrict__ KH, const unsigned short* __restrict__ KL,
              const unsigned short* __restrict__ VH, unsigned short* __restrict__ Op,
              int str1, int str2, int strE) {
  __shared__ __align__(16) unsigned short L[16384];  // 32 KiB union
  // Loop A: Kh[b] @ b*4096 ; Kl[b] @ 8192 + b*4096
  // Loop B: Vt[b] @ b*4096 ; Ps @ 8192 ; epilogue Otile @ 0 (stride 72)

  int bi = (blockIdx.x & 7) * 432 + (blockIdx.x >> 3);  // bijective XCD swizzle
  const int qt   = bi % NTILE;
  const int head = (bi / NTILE) & 7;
  const int be   = bi / (NTILE * NHEAD);
  const int bb   = be / 24;
  const int e    = be % 24;

  const int tid  = threadIdx.x;
  const int w    = tid >> 6;
  const int lane = tid & 63;
  const int l15  = lane & 15;
  const int lg   = lane >> 4;

  const size_t base_tok = (size_t)bb * NTOK + (size_t)e * strE;
  const size_t pb = ((size_t)head * M_TOT + base_tok) * 64;
  const unsigned short* qhp = QH + pb;
  const unsigned short* qlp = QL + pb;
  const unsigned short* khp = KH + pb;
  const unsigned short* klp = KL + pb;
  const unsigned short* vhp = VH + pb;

  // ---- Q fragments (pre-scaled, pre-split) ----
  s16x8 qh[2], ql[2];
  {
    int s  = qt * 64 + w * 16 + l15;
    size_t no = (size_t)((s / 24) * str1 + (s % 24) * str2) * 64 + lg * 8;
    qh[0] = *(const s16x8*)(qhp + no);
    qh[1] = *(const s16x8*)(qhp + no + 32);
    ql[0] = *(const s16x8*)(qlp + no);
    ql[1] = *(const s16x8*)(qlp + no + 32);
  }

  const f32x4 fz = {0.0f, 0.0f, 0.0f, 0.0f};
  f32x4 S[NTILE][4];

  // K staging map: cc = 16B chunk (d0=cc*8), rows r0 and r0+32
  const int cc = tid & 7;
  const int r0 = tid >> 3;

  s16x8 kr[2][2], lr[2][2];
#pragma unroll
  for (int hf = 0; hf < 2; ++hf) {
    int s = r0 + hf * 32;
    size_t no = (size_t)((s / 24) * str1 + (s % 24) * str2) * 64 + cc * 8;
    kr[0][hf] = *(const s16x8*)(khp + no);
    lr[0][hf] = *(const s16x8*)(klp + no);
  }

  // ================= Loop A: S = Q K^T (all 9 tiles) =================
#pragma unroll
  for (int t = 0; t < NTILE; ++t) {
    const int b = t & 1;
#pragma unroll
    for (int hf = 0; hf < 2; ++hf) {
      int r = r0 + hf * 32;
      int off = b * 4096 + (r << 6) + ((cc ^ (r & 7)) << 3);
      *(s16x8*)&L[off]        = kr[b][hf];
      *(s16x8*)&L[8192 + off] = lr[b][hf];
    }
    if (t < NTILE - 1) {
#pragma unroll
      for (int hf = 0; hf < 2; ++hf) {
        int s = (t + 1) * 64 + r0 + hf * 32;
        size_t no = (size_t)((s / 24) * str1 + (s % 24) * str2) * 64 + cc * 8;
        kr[b ^ 1][hf] = *(const s16x8*)(khp + no);
        lr[b ^ 1][hf] = *(const s16x8*)(klp + no);
      }
    }
    asm volatile("s_waitcnt lgkmcnt(0)" ::: "memory");
    __builtin_amdgcn_s_barrier();
    __builtin_amdgcn_s_setprio(1);
#pragma unroll
    for (int n = 0; n < 4; ++n) S[t][n] = fz;
#pragma unroll
    for (int ks = 0; ks < 2; ++ks) {
#pragma unroll
      for (int n = 0; n < 4; ++n) {
        int krow = (n << 4) + l15;
        int off  = b * 4096 + (krow << 6) + (((ks * 4 + lg) ^ (krow & 7)) << 3);
        s16x8 kfh = *(const s16x8*)&L[off];
        s16x8 kfl = *(const s16x8*)&L[8192 + off];
        S[t][n] = __builtin_amdgcn_mfma_f32_16x16x32_bf16(qh[ks], kfh, S[t][n], 0, 0, 0);
        S[t][n] = __builtin_amdgcn_mfma_f32_16x16x32_bf16(ql[ks], kfh, S[t][n], 0, 0, 0);
        S[t][n] = __builtin_amdgcn_mfma_f32_16x16x32_bf16(qh[ks], kfl, S[t][n], 0, 0, 0);
      }
    }
    __builtin_amdgcn_s_setprio(0);
  }

  // ---- issue V tile-0 loads now (hide HBM latency under softmax) ----
  const int rp = (tid & 31) * 2;   // token pair
  const int cb = tid >> 5;         // d chunk 0..7
  s16x8 vr[2][2];
#pragma unroll
  for (int pp = 0; pp < 2; ++pp) {
    int s = rp + pp;
    size_t no = (size_t)((s / 24) * str1 + (s % 24) * str2) * 64 + cb * 8;
    vr[0][pp] = *(const s16x8*)(vhp + no);
  }

  // ================= one deferred softmax (base 2) =================
  float linv[4];
#pragma unroll
  for (int rr = 0; rr < 4; ++rr) {
    float m0 = S[0][0][rr];
#pragma unroll
    for (int t = 0; t < NTILE; ++t)
#pragma unroll
      for (int n = 0; n < 4; ++n) m0 = fmaxf(m0, S[t][n][rr]);
    m0 = fmaxf(m0, __shfl_xor(m0, 1));
    m0 = fmaxf(m0, __shfl_xor(m0, 2));
    m0 = fmaxf(m0, __shfl_xor(m0, 4));
    m0 = fmaxf(m0, __shfl_xor(m0, 8));
    float ts = 0.0f;
#pragma unroll
    for (int t = 0; t < NTILE; ++t)
#pragma unroll
      for (int n = 0; n < 4; ++n) {
        float p = exp2f(S[t][n][rr] - m0);
        S[t][n][rr] = p;
        ts += p;
      }
    ts += __shfl_xor(ts, 1);
    ts += __shfl_xor(ts, 2);
    ts += __shfl_xor(ts, 4);
    ts += __shfl_xor(ts, 8);
    linv[rr] = 1.0f / ts;
  }

  __syncthreads();   // all loop-A LDS reads retired before V overwrites

  // ================= Loop B: O = P V =================
  f32x4 Ov[4];
#pragma unroll
  for (int n = 0; n < 4; ++n) Ov[n] = fz;
  const int prow = (w << 4) + (lg << 2);

#pragma unroll
  for (int t = 0; t < NTILE; ++t) {
    const int b = t & 1;
    // V -> LDS transposed [d][tok], u32 token-pair packs
#pragma unroll
    for (int j = 0; j < 8; ++j) {
      int d = cb * 8 + j;
      unsigned pk = (unsigned)(unsigned short)vr[b][0][j] |
                    ((unsigned)(unsigned short)vr[b][1][j] << 16);
      int off = b * 4096 + (d << 6) + (((rp >> 3) ^ (d & 7)) << 3) + (rp & 7);
      *(unsigned*)&L[off] = pk;
    }
    if (t < NTILE - 1) {
#pragma unroll
      for (int pp = 0; pp < 2; ++pp) {
        int s = (t + 1) * 64 + rp + pp;
        size_t no = (size_t)((s / 24) * str1 + (s % 24) * str2) * 64 + cb * 8;
        vr[b ^ 1][pp] = *(const s16x8*)(vhp + no);
      }
    }
    // P (bf16) -> Ps, own-wave rows
#pragma unroll
    for (int n = 0; n < 4; ++n) {
      int col = (n << 4) + l15;
#pragma unroll
      for (int rr = 0; rr < 4; ++rr) {
        int row = prow + rr;
        int off = 8192 + (row << 6) + (((col >> 3) ^ (row & 7)) << 3) + (col & 7);
        L[off] = f2bf(S[t][n][rr]);
      }
    }
    asm volatile("s_waitcnt lgkmcnt(0)" ::: "memory");
    __builtin_amdgcn_s_barrier();
    __builtin_amdgcn_s_setprio(1);
#pragma unroll
    for (int ks = 0; ks < 2; ++ks) {
      int arow = (w << 4) + l15;
      int aoff = 8192 + (arow << 6) + (((ks * 4 + lg) ^ (arow & 7)) << 3);
      s16x8 pa = *(const s16x8*)&L[aoff];
#pragma unroll
      for (int n = 0; n < 4; ++n) {
        int vrow = (n << 4) + l15;
        int voff = b * 4096 + (vrow << 6) + (((ks * 4 + lg) ^ (vrow & 7)) << 3);
        s16x8 vb = *(const s16x8*)&L[voff];
        Ov[n] = __builtin_amdgcn_mfma_f32_16x16x32_bf16(pa, vb, Ov[n], 0, 0, 0);
      }
    }
    __builtin_amdgcn_s_setprio(0);
  }

  // ================= epilogue: transpose via LDS, 128B-row writes ========
  __syncthreads();
#pragma unroll
  for (int n = 0; n < 4; ++n) {
#pragma unroll
    for (int rr = 0; rr < 4; ++rr) {
      int row = prow + rr;
      int col = (n << 4) + l15;
      L[row * 72 + col] = f2bf(Ov[n][rr] * linv[rr]);
    }
  }
  __syncthreads();
#pragma unroll
  for (int it = 0; it < 2; ++it) {
    int q   = it * 256 + tid;
    int row = q >> 3, c8 = q & 7;
    s16x8 ov = *(const s16x8*)&L[row * 72 + c8 * 8];
    int s = qt * 64 + row;
    size_t no = (size_t)((s / 24) * str1 + (s % 24) * str2) * 64 + c8 * 8;
    *(s16x8*)(Op + pb + no) = ov;
  }
}

// ---------------------------------------------------------------------------
extern "C" void kernel_launch(void* const* d_in, const int* in_sizes, int n_in,
                              void* d_out, int out_size, void* d_ws, size_t ws_size,
                              hipStream_t stream) {
  (void)in_sizes; (void)n_in; (void)out_size; (void)ws_size;
  const float* x      = (const float*)d_in[0];
  const float* w_qkv  = (const float*)d_in[1];
  const float* w_proj = (const float*)d_in[2];
  float* out = (float*)d_out;

  // ---- workspace layout (~230 MB peak) ----
  char* ws = (char*)d_ws;
  constexpr size_t PL_E = (size_t)NHEAD * M_TOT * 64;     // elems per plane
  constexpr size_t PL_B = PL_E * 2;                       // 28,311,552 B
  unsigned short* QHp = (unsigned short*)ws;
  unsigned short* QLp = QHp + PL_E;
  unsigned short* KHp = QHp + 2 * PL_E;
  unsigned short* KLp = QHp + 3 * PL_E;
  unsigned short* VHp = QHp + 4 * PL_E;
  unsigned short* O0  = QHp + 5 * PL_E;
  unsigned short* O1  = QHp + 6 * PL_E;
  unsigned short* O2  = QHp + 7 * PL_E;
  s16x8* Bh = (s16x8*)(ws + 8 * PL_B);                    // w_qkv hi (1.57 MB)
  s16x8* Bl = (s16x8*)(ws + 8 * PL_B + 1572864);
  s16x8* Ah = (s16x8*)(ws + 5 * PL_B);                    // overlay O0 (dead before attn)
  s16x8* Al = (s16x8*)(ws + 6 * PL_B);                    // overlay O1
  s16x8* Oh = (s16x8*)ws;                                 // overlay QH (dead after attn)
  s16x8* Ph = (s16x8*)(ws + PL_B);                        // overlay QL

  unsigned short* nu = nullptr;

  // 1) operand conversion (fragment-major)
  conv_a_frag<true><<<M_TOT * 64 / 256, 256, 0, stream>>>(x, Ah, Al);
  conv_b_frag<true><<<KT * (QKV_LD / 16) * 64 / 256, 256, 0, stream>>>(w_qkv, Bh, Bl, QKV_LD);

  // 2) qkv GEMM -> bf16 planes (q,k split hi/lo + q scaled; v plain)
  gemm_frag<3, 1><<<(M_TOT / 128) * 8, 256, 0, stream>>>(
      Ah, Al, Bh, Bl, nullptr, QHp, QLp, KHp, KLp, 8, 0, 0, 0);
  gemm_frag<1, 2><<<(M_TOT / 128) * 4, 256, 0, stream>>>(
      Ah, nullptr, Bh, nullptr, nullptr, VHp, nu, nu, nu, 4, 0, 0, 64);

  // 3) three decomposed attentions -> separate bf16 O planes (no RMW)
  attn_def<<<48 * NHEAD * NTILE, 256, 0, stream>>>(QHp, QLp, KHp, KLp, VHp, O0, 576, 24, 1);
  attn_def<<<48 * NHEAD * NTILE, 256, 0, stream>>>(QHp, QLp, KHp, KLp, VHp, O1, 576, 1, 24);
  attn_def<<<48 * NHEAD * NTILE, 256, 0, stream>>>(QHp, QLp, KHp, KLp, VHp, O2, 24, 1, 576);

  // 4) proj GEMM: out = (O0+O1+O2) @ w_proj (plain bf16)
  conv_o_frag<<<M_TOT * 64 / 256, 256, 0, stream>>>(O0, O1, O2, Oh);
  conv_b_frag<false><<<KT * (Cc / 16) * 64 / 256, 256, 0, stream>>>(w_proj, Ph, nullptr, Cc);
  gemm_frag<1, 0><<<(M_TOT / 128) * 4, 256, 0, stream>>>(
      Oh, nullptr, Ph, nullptr, out, nu, nu, nu, nu, 4, 0, Cc, 0);
}

// Round 9
// 577.070 us; speedup vs baseline: 1.6665x; 1.1470x over previous
//
#include <hip/hip_runtime.h>
#include <math.h>

// Problem constants (fixed by setup_inputs: b=2, H=W=T=24, c=512, heads=8)
constexpr int Cc     = 512;
constexpr int NHEAD  = 8;
constexpr int HD     = 64;
constexpr int NTOK   = 13824;          // tokens per batch element (24^3)
constexpr int BATCH  = 2;
constexpr int M_TOT  = BATCH * NTOK;   // 27648 total rows
constexpr int QKV_LD = 3 * Cc;         // 1536
constexpr int SEQLEN = 576;            // 24*24 per decomposed attention
constexpr int NTILE  = SEQLEN / 64;    // 9 k-tiles of 64
constexpr int KT     = 16;             // K=512 / 32 per MFMA step (all GEMMs)
constexpr size_t PL_E = (size_t)NHEAD * M_TOT * 64;   // elems per head-major plane

// q-plane scale: sqrt(hd)=8 folded with log2(e) so softmax uses exp2
#define QSCALE 11.541560327111707f

typedef short s16x8 __attribute__((ext_vector_type(8)));
typedef short s16x4 __attribute__((ext_vector_type(4)));
typedef float f32x4 __attribute__((ext_vector_type(4)));
typedef unsigned u32x2 __attribute__((ext_vector_type(2)));

__device__ __forceinline__ unsigned short f2bf(float f) {
  unsigned u = __float_as_uint(f);
  unsigned r = u + 0x7fffu + ((u >> 16) & 1u);
  return (unsigned short)(r >> 16);
}
__device__ __forceinline__ float bf2f(unsigned short b) {
  return __uint_as_float(((unsigned)b) << 16);
}
__device__ __forceinline__ unsigned cvtpk_bf16(float lo, float hi) {
  unsigned r;
  asm("v_cvt_pk_bf16_f32 %0, %1, %2" : "=v"(r) : "v"(lo), "v"(hi));
  return r;
}
// PV matrix op: K=16 MFMA whose A-frag layout (row=lane&15, k=4*(lane>>4)+j)
// matches the swapped-QK^T S^T fragment exactly -> P never leaves registers.
// s_nop guards the VALU(cvt_pk)->MFMA-src hazard (asm bypasses compiler's
// hazard recognizer).
__device__ __forceinline__ void pv_mfma16(f32x4& d, s16x4 a, s16x4 b) {
  asm("s_nop 1\n\tv_mfma_f32_16x16x16_bf16 %0, %1, %2, %0"
      : "+v"(d) : "v"(a), "v"(b));
}

// ---------------------------------------------------------------------------
// Convert fp32 row-major A[M][512] into fragment-major bf16 (hi, optional lo).
// ---------------------------------------------------------------------------
template<bool WRITE_LO>
__global__ __launch_bounds__(256)
void conv_a_frag(const float* __restrict__ src, s16x8* __restrict__ dh,
                 s16x8* __restrict__ dl) {
  int g  = blockIdx.x * 256 + threadIdx.x;
  int l  = g & 63;
  int t  = g >> 6;
  int kt = t & (KT - 1);
  int mt = t >> 4;
  const float* p = src + (size_t)(mt * 16 + (l & 15)) * 512 + kt * 32 + (l >> 4) * 8;
  float4 a = *(const float4*)p;
  float4 b = *(const float4*)(p + 4);
  float xs[8] = {a.x, a.y, a.z, a.w, b.x, b.y, b.z, b.w};
  s16x8 h, lo;
#pragma unroll
  for (int j = 0; j < 8; ++j) {
    unsigned short hh = f2bf(xs[j]);
    h[j] = (short)hh;
    if (WRITE_LO) lo[j] = (short)f2bf(xs[j] - bf2f(hh));
  }
  dh[g] = h;
  if (WRITE_LO) dl[g] = lo;
}

// ---------------------------------------------------------------------------
// Convert fp32 row-major B[512][N] into fragment-major bf16 (hi, optional lo).
// ---------------------------------------------------------------------------
template<bool WRITE_LO>
__global__ __launch_bounds__(256)
void conv_b_frag(const float* __restrict__ src, s16x8* __restrict__ dh,
                 s16x8* __restrict__ dl, int N) {
  int g  = blockIdx.x * 256 + threadIdx.x;
  int l  = g & 63;
  int t  = g >> 6;
  int kt = t & (KT - 1);
  int nt = t >> 4;
  int col  = nt * 16 + (l & 15);
  int row0 = kt * 32 + (l >> 4) * 8;
  s16x8 h, lo;
#pragma unroll
  for (int j = 0; j < 8; ++j) {
    float v = src[(size_t)(row0 + j) * N + col];
    unsigned short hh = f2bf(v);
    h[j] = (short)hh;
    if (WRITE_LO) lo[j] = (short)f2bf(v - bf2f(hh));
  }
  dh[g] = h;
  if (WRITE_LO) dl[g] = lo;
}

// ---------------------------------------------------------------------------
// Sum three attention O planes (head-major bf16) -> proj A fragments.
// ---------------------------------------------------------------------------
__global__ __launch_bounds__(256)
void conv_o_frag(const unsigned short* __restrict__ O0,
                 const unsigned short* __restrict__ O1,
                 const unsigned short* __restrict__ O2,
                 s16x8* __restrict__ dh) {
  int g  = blockIdx.x * 256 + threadIdx.x;
  int l  = g & 63;
  int t  = g >> 6;
  int kt = t & (KT - 1);
  int mt = t >> 4;
  int row = mt * 16 + (l & 15);
  int c0  = kt * 32 + (l >> 4) * 8;
  int head = c0 >> 6;
  size_t off = ((size_t)head * M_TOT + row) * 64 + (c0 & 63);
  s16x8 a = *(const s16x8*)(O0 + off);
  s16x8 b = *(const s16x8*)(O1 + off);
  s16x8 c = *(const s16x8*)(O2 + off);
  s16x8 h;
#pragma unroll
  for (int j = 0; j < 8; ++j) {
    float v = bf2f((unsigned short)a[j]) + bf2f((unsigned short)b[j]) +
              bf2f((unsigned short)c[j]);
    h[j] = (short)f2bf(v);
  }
  dh[g] = h;
}

// ---------------------------------------------------------------------------
// No-LDS MFMA GEMM on fragment-major bf16 operands (unchanged, proven).
// ---------------------------------------------------------------------------
template<int SPLIT, int MODE>
__global__ __launch_bounds__(256)
void gemm_frag(const s16x8* __restrict__ Ah, const s16x8* __restrict__ Al,
               const s16x8* __restrict__ Bh, const s16x8* __restrict__ Bl,
               float* __restrict__ C,
               unsigned short* __restrict__ p0, unsigned short* __restrict__ p1,
               unsigned short* __restrict__ p2, unsigned short* __restrict__ p3,
               int nbx, int n0, int N_ld, int ntoff) {
  int nwg = gridDim.x;
  int cpx = nwg >> 3;
  int bid = blockIdx.x;
  int swz = (bid & 7) * cpx + (bid >> 3);
  int bx = swz % nbx;
  int by = swz / nbx;

  int tid  = threadIdx.x;
  int lane = tid & 63;
  int w    = tid >> 6;
  int wm   = w & 1;
  int wn   = w >> 1;
  int mt0  = by * 8 + wm * 4;
  int ntG  = ntoff + bx * 8 + wn * 4;

  const f32x4 fz = {0.0f, 0.0f, 0.0f, 0.0f};
  f32x4 acc[4][4];
#pragma unroll
  for (int mi = 0; mi < 4; ++mi)
#pragma unroll
    for (int ni = 0; ni < 4; ++ni) acc[mi][ni] = fz;

#pragma unroll 2
  for (int kt = 0; kt < KT; ++kt) {
    s16x8 ah[4], bh[4];
#pragma unroll
    for (int mi = 0; mi < 4; ++mi)
      ah[mi] = Ah[(size_t)(((mt0 + mi) * KT + kt) * 64 + lane)];
#pragma unroll
    for (int ni = 0; ni < 4; ++ni)
      bh[ni] = Bh[(size_t)(((ntG + ni) * KT + kt) * 64 + lane)];

    if constexpr (SPLIT == 3) {
      s16x8 al[4], bl[4];
#pragma unroll
      for (int mi = 0; mi < 4; ++mi)
        al[mi] = Al[(size_t)(((mt0 + mi) * KT + kt) * 64 + lane)];
#pragma unroll
      for (int ni = 0; ni < 4; ++ni)
        bl[ni] = Bl[(size_t)(((ntG + ni) * KT + kt) * 64 + lane)];
#pragma unroll
      for (int mi = 0; mi < 4; ++mi)
#pragma unroll
        for (int ni = 0; ni < 4; ++ni) {
          acc[mi][ni] = __builtin_amdgcn_mfma_f32_16x16x32_bf16(ah[mi], bh[ni], acc[mi][ni], 0, 0, 0);
          acc[mi][ni] = __builtin_amdgcn_mfma_f32_16x16x32_bf16(al[mi], bh[ni], acc[mi][ni], 0, 0, 0);
          acc[mi][ni] = __builtin_amdgcn_mfma_f32_16x16x32_bf16(ah[mi], bl[ni], acc[mi][ni], 0, 0, 0);
        }
    } else {
#pragma unroll
      for (int mi = 0; mi < 4; ++mi)
#pragma unroll
        for (int ni = 0; ni < 4; ++ni)
          acc[mi][ni] = __builtin_amdgcn_mfma_f32_16x16x32_bf16(ah[mi], bh[ni], acc[mi][ni], 0, 0, 0);
    }
  }

  int lg = lane >> 4, l15 = lane & 15;
  if constexpr (MODE == 0) {
#pragma unroll
    for (int mi = 0; mi < 4; ++mi) {
#pragma unroll
      for (int r = 0; r < 4; ++r) {
        int row = by * 128 + wm * 64 + mi * 16 + lg * 4 + r;
        float* cp = C + (size_t)row * N_ld + n0 + bx * 128 + wn * 64 + l15;
#pragma unroll
        for (int ni = 0; ni < 4; ++ni) cp[ni * 16] = acc[mi][ni][r];
      }
    }
  } else {
    int colb = bx * 128 + wn * 64;
    int head = (colb >> 6) & 7;
    const bool isq = (MODE == 1) && (colb < 512);
    unsigned short* Hp;
    unsigned short* Lp = nullptr;
    float sc = 1.0f;
    if (MODE == 2)      { Hp = p0; }
    else if (isq)       { Hp = p0; Lp = p1; sc = QSCALE; }
    else                { Hp = p2; Lp = p3; }
    size_t hb = (size_t)head * ((size_t)M_TOT * 64);
#pragma unroll
    for (int mi = 0; mi < 4; ++mi) {
#pragma unroll
      for (int r = 0; r < 4; ++r) {
        int row = by * 128 + wm * 64 + mi * 16 + lg * 4 + r;
        size_t base = hb + (size_t)row * 64;
#pragma unroll
        for (int ni = 0; ni < 4; ++ni) {
          int d = ni * 16 + l15;
          float v = acc[mi][ni][r] * sc;
          unsigned short hh = f2bf(v);
          Hp[base + d] = hh;
          if (MODE == 1) Lp[base + d] = f2bf(v - bf2f(hh));
        }
      }
    }
  }
}

// ---------------------------------------------------------------------------
// Fused 3-pass attention. Block = 4 waves, (pass, be, head, qt=64 rows).
// Swapped QK^T (S^T = mfma(K, Q)): lane holds q=lane&15, k=16n+4lg+r.
//  -> softmax reduce = 2 shuffles; PV A-frag = S^T directly via 16x16x16 MFMA.
// Online softmax with defer-max (THR=8 in log2): rescale almost never fires.
// K hi/lo + Vt LDS tiles double-buffered (48 KiB), 1 barrier/tile, reg-staged
// prefetch of tile t+1 under tile t's MFMA.
// ---------------------------------------------------------------------------
__global__ __launch_bounds__(256, 3)
void attn_fused(const unsigned short* __restrict__ QH, const unsigned short* __restrict__ QL,
                const unsigned short* __restrict__ KH, const unsigned short* __restrict__ KL,
                const unsigned short* __restrict__ VH, unsigned short* __restrict__ Oall) {
  __shared__ __align__(16) unsigned short L[24576]; // Khi[2]@0, Kl[2]@8192, Vt[2]@16384

  const int p  = blockIdx.x / 3456;
  const int rr_ = blockIdx.x % 3456;
  const int bi = (rr_ & 7) * 432 + (rr_ >> 3);      // bijective XCD swizzle
  const int str1 = (p == 2) ? 24 : 576;
  const int str2 = (p == 0) ? 24 : 1;
  const int strE = (p == 0) ? 1 : (p == 1 ? 24 : 576);

  const int qt   = bi % NTILE;
  const int head = (bi / NTILE) & 7;
  const int be   = bi / (NTILE * NHEAD);
  const int bb   = be / 24;
  const int e    = be % 24;

  const int tid  = threadIdx.x;
  const int w    = tid >> 6;
  const int lane = tid & 63;
  const int l15  = lane & 15;
  const int lg   = lane >> 4;

  const size_t base_tok = (size_t)bb * NTOK + (size_t)e * strE;
  const size_t pb = ((size_t)head * M_TOT + base_tok) * 64;
  const unsigned short* qhp = QH + pb;
  const unsigned short* qlp = QL + pb;
  const unsigned short* khp = KH + pb;
  const unsigned short* klp = KL + pb;
  const unsigned short* vhp = VH + pb;
  unsigned short* Op = Oall + (size_t)p * PL_E;

  // ---- Q fragments (pre-scaled by QSCALE, pre-split hi/lo) ----
  s16x8 qh[2], ql[2];
  {
    int s  = qt * 64 + w * 16 + l15;
    size_t no = (size_t)((s / 24) * str1 + (s % 24) * str2) * 64 + lg * 8;
    qh[0] = *(const s16x8*)(qhp + no);
    qh[1] = *(const s16x8*)(qhp + no + 32);
    ql[0] = *(const s16x8*)(qlp + no);
    ql[1] = *(const s16x8*)(qlp + no + 32);
  }

  // staging maps
  const int cc = tid & 7;          // K: 16B d-chunk
  const int r0 = tid >> 3;         // K: token rows r0, r0+32
  const int rp = (tid & 31) * 2;   // V: token pair
  const int cb = tid >> 5;         // V: d chunk 0..7

  s16x8 kr[2][2], lr[2][2], vr[2][2];
#pragma unroll
  for (int hf = 0; hf < 2; ++hf) {
    int s = r0 + hf * 32;
    size_t no = (size_t)((s / 24) * str1 + (s % 24) * str2) * 64 + cc * 8;
    kr[0][hf] = *(const s16x8*)(khp + no);
    lr[0][hf] = *(const s16x8*)(klp + no);
  }
#pragma unroll
  for (int pp = 0; pp < 2; ++pp) {
    int s = rp + pp;
    size_t no = (size_t)((s / 24) * str1 + (s % 24) * str2) * 64 + cb * 8;
    vr[0][pp] = *(const s16x8*)(vhp + no);
  }

  const f32x4 fz = {0.0f, 0.0f, 0.0f, 0.0f};
  f32x4 Ov[4];
#pragma unroll
  for (int n = 0; n < 4; ++n) Ov[n] = fz;
  float m_run = -1e30f, l_run = 0.0f;

#pragma unroll
  for (int t = 0; t < NTILE; ++t) {
    const int b = t & 1;
    // ---- stage K hi/lo + Vt from regs ----
#pragma unroll
    for (int hf = 0; hf < 2; ++hf) {
      int r = r0 + hf * 32;
      int off = b * 4096 + (r << 6) + ((cc ^ (r & 7)) << 3);
      *(s16x8*)&L[off]        = kr[b][hf];
      *(s16x8*)&L[8192 + off] = lr[b][hf];
    }
#pragma unroll
    for (int j = 0; j < 8; ++j) {
      int d = cb * 8 + j;
      unsigned pk = (unsigned)(unsigned short)vr[b][0][j] |
                    ((unsigned)(unsigned short)vr[b][1][j] << 16);
      int off = 16384 + b * 4096 + (d << 6) + (((rp >> 3) ^ (d & 7)) << 3) + (rp & 7);
      *(unsigned*)&L[off] = pk;
    }
    // ---- prefetch t+1 ----
    if (t < NTILE - 1) {
#pragma unroll
      for (int hf = 0; hf < 2; ++hf) {
        int s = (t + 1) * 64 + r0 + hf * 32;
        size_t no = (size_t)((s / 24) * str1 + (s % 24) * str2) * 64 + cc * 8;
        kr[b ^ 1][hf] = *(const s16x8*)(khp + no);
        lr[b ^ 1][hf] = *(const s16x8*)(klp + no);
      }
#pragma unroll
      for (int pp = 0; pp < 2; ++pp) {
        int s = (t + 1) * 64 + rp + pp;
        size_t no = (size_t)((s / 24) * str1 + (s % 24) * str2) * 64 + cb * 8;
        vr[b ^ 1][pp] = *(const s16x8*)(vhp + no);
      }
    }
    asm volatile("s_waitcnt lgkmcnt(0)" ::: "memory");
    __builtin_amdgcn_s_barrier();

    // ---- S^T = K (Qh+Ql)^T, 3 terms ----
    f32x4 Sv[4];
#pragma unroll
    for (int n = 0; n < 4; ++n) Sv[n] = fz;
    __builtin_amdgcn_s_setprio(1);
#pragma unroll
    for (int ks = 0; ks < 2; ++ks) {
#pragma unroll
      for (int n = 0; n < 4; ++n) {
        int krow = (n << 4) + l15;
        int off  = b * 4096 + (krow << 6) + (((ks * 4 + lg) ^ (krow & 7)) << 3);
        s16x8 kfh = *(const s16x8*)&L[off];
        s16x8 kfl = *(const s16x8*)&L[8192 + off];
        Sv[n] = __builtin_amdgcn_mfma_f32_16x16x32_bf16(kfh, qh[ks], Sv[n], 0, 0, 0);
        Sv[n] = __builtin_amdgcn_mfma_f32_16x16x32_bf16(kfl, qh[ks], Sv[n], 0, 0, 0);
        Sv[n] = __builtin_amdgcn_mfma_f32_16x16x32_bf16(kfh, ql[ks], Sv[n], 0, 0, 0);
      }
    }
    __builtin_amdgcn_s_setprio(0);

    // ---- online softmax (base 2), defer-max THR=8 ----
    float vmax = Sv[0][0];
#pragma unroll
    for (int n = 0; n < 4; ++n)
#pragma unroll
      for (int r = 0; r < 4; ++r) vmax = fmaxf(vmax, Sv[n][r]);
    vmax = fmaxf(vmax, __shfl_xor(vmax, 16));
    vmax = fmaxf(vmax, __shfl_xor(vmax, 32));
    if (!__all(vmax <= m_run + 8.0f)) {
      float mn = fmaxf(m_run, vmax);
      float alpha = exp2f(m_run - mn);
      m_run = mn;
      l_run *= alpha;
      float a0 = __shfl(alpha, lg * 4 + 0);
      float a1 = __shfl(alpha, lg * 4 + 1);
      float a2 = __shfl(alpha, lg * 4 + 2);
      float a3 = __shfl(alpha, lg * 4 + 3);
#pragma unroll
      for (int n = 0; n < 4; ++n) {
        Ov[n][0] *= a0; Ov[n][1] *= a1; Ov[n][2] *= a2; Ov[n][3] *= a3;
      }
    }
    float ts = 0.0f;
#pragma unroll
    for (int n = 0; n < 4; ++n)
#pragma unroll
      for (int r = 0; r < 4; ++r) {
        float pv = exp2f(Sv[n][r] - m_run);
        Sv[n][r] = pv;
        ts += pv;
      }
    ts += __shfl_xor(ts, 16);
    ts += __shfl_xor(ts, 32);
    l_run += ts;

    // ---- P (registers!) -> bf16 A-frags for K=16 MFMA ----
    s16x4 pa[4];
#pragma unroll
    for (int n = 0; n < 4; ++n) {
      u32x2 t2;
      t2[0] = cvtpk_bf16(Sv[n][0], Sv[n][1]);
      t2[1] = cvtpk_bf16(Sv[n][2], Sv[n][3]);
      pa[n] = __builtin_bit_cast(s16x4, t2);
    }
    // ---- O += P V via 16 x mfma_16x16x16 ----
#pragma unroll
    for (int n = 0; n < 4; ++n) {
      int d = n * 16 + l15;
      int dbase = 16384 + b * 4096 + (d << 6);
      int dx = d & 7;
#pragma unroll
      for (int kb = 0; kb < 4; ++kb) {
        int chunk = 2 * kb + (lg >> 1);
        int off = dbase + ((chunk ^ dx) << 3) + ((lg & 1) << 2);
        s16x4 vb = *(const s16x4*)&L[off];
        pv_mfma16(Ov[n], pa[kb], vb);
      }
    }
    __builtin_amdgcn_sched_barrier(0);  // keep later O-reads after the asm MFMAs
  }

  // ---- epilogue: hazard guard, normalize, LDS transpose, 128B-row writes ----
  asm volatile("s_nop 7\n\ts_nop 7" :::);
  float linv = 1.0f / l_run;
  float l0 = __shfl(linv, lg * 4 + 0);
  float l1 = __shfl(linv, lg * 4 + 1);
  float l2 = __shfl(linv, lg * 4 + 2);
  float l3 = __shfl(linv, lg * 4 + 3);
  __syncthreads();
  const int prow = (w << 4) + (lg << 2);
#pragma unroll
  for (int n = 0; n < 4; ++n) {
    int col = (n << 4) + l15;
    L[(prow + 0) * 72 + col] = f2bf(Ov[n][0] * l0);
    L[(prow + 1) * 72 + col] = f2bf(Ov[n][1] * l1);
    L[(prow + 2) * 72 + col] = f2bf(Ov[n][2] * l2);
    L[(prow + 3) * 72 + col] = f2bf(Ov[n][3] * l3);
  }
  __syncthreads();
#pragma unroll
  for (int it = 0; it < 2; ++it) {
    int q   = it * 256 + tid;
    int row = q >> 3, c8 = q & 7;
    s16x8 ov = *(const s16x8*)&L[row * 72 + c8 * 8];
    int s = qt * 64 + row;
    size_t no = (size_t)((s / 24) * str1 + (s % 24) * str2) * 64 + c8 * 8;
    *(s16x8*)(Op + pb + no) = ov;
  }
}

// ---------------------------------------------------------------------------
extern "C" void kernel_launch(void* const* d_in, const int* in_sizes, int n_in,
                              void* d_out, int out_size, void* d_ws, size_t ws_size,
                              hipStream_t stream) {
  (void)in_sizes; (void)n_in; (void)out_size; (void)ws_size;
  const float* x      = (const float*)d_in[0];
  const float* w_qkv  = (const float*)d_in[1];
  const float* w_proj = (const float*)d_in[2];
  float* out = (float*)d_out;

  // ---- workspace layout (~230 MB peak) ----
  char* ws = (char*)d_ws;
  constexpr size_t PL_B = PL_E * 2;                       // 28,311,552 B
  unsigned short* QHp = (unsigned short*)ws;
  unsigned short* QLp = QHp + PL_E;
  unsigned short* KHp = QHp + 2 * PL_E;
  unsigned short* KLp = QHp + 3 * PL_E;
  unsigned short* VHp = QHp + 4 * PL_E;
  unsigned short* O0  = QHp + 5 * PL_E;
  unsigned short* O1  = QHp + 6 * PL_E;
  unsigned short* O2  = QHp + 7 * PL_E;
  s16x8* Bh = (s16x8*)(ws + 8 * PL_B);                    // w_qkv hi (1.57 MB)
  s16x8* Bl = (s16x8*)(ws + 8 * PL_B + 1572864);
  s16x8* Ah = (s16x8*)(ws + 5 * PL_B);                    // overlay O0 (dead before attn)
  s16x8* Al = (s16x8*)(ws + 6 * PL_B);                    // overlay O1
  s16x8* Oh = (s16x8*)ws;                                 // overlay QH (dead after attn)
  s16x8* Ph = (s16x8*)(ws + PL_B);                        // overlay QL

  unsigned short* nu = nullptr;

  // 1) operand conversion (fragment-major)
  conv_a_frag<true><<<M_TOT * 64 / 256, 256, 0, stream>>>(x, Ah, Al);
  conv_b_frag<true><<<KT * (QKV_LD / 16) * 64 / 256, 256, 0, stream>>>(w_qkv, Bh, Bl, QKV_LD);

  // 2) qkv GEMM -> bf16 planes (q,k split hi/lo + q scaled; v plain)
  gemm_frag<3, 1><<<(M_TOT / 128) * 8, 256, 0, stream>>>(
      Ah, Al, Bh, Bl, nullptr, QHp, QLp, KHp, KLp, 8, 0, 0, 0);
  gemm_frag<1, 2><<<(M_TOT / 128) * 4, 256, 0, stream>>>(
      Ah, nullptr, Bh, nullptr, nullptr, VHp, nu, nu, nu, 4, 0, 0, 64);

  // 3) fused 3-pass attention -> three bf16 O planes
  attn_fused<<<3 * 48 * NHEAD * NTILE, 256, 0, stream>>>(QHp, QLp, KHp, KLp, VHp, O0);

  // 4) proj GEMM: out = (O0+O1+O2) @ w_proj (plain bf16)
  conv_o_frag<<<M_TOT * 64 / 256, 256, 0, stream>>>(O0, O1, O2, Oh);
  conv_b_frag<false><<<KT * (Cc / 16) * 64 / 256, 256, 0, stream>>>(w_proj, Ph, nullptr, Cc);
  gemm_frag<1, 0><<<(M_TOT / 128) * 4, 256, 0, stream>>>(
      Oh, nullptr, Ph, nullptr, out, nu, nu, nu, nu, 4, 0, Cc, 0);
}